// Round 9
// baseline (239.893 us; speedup 1.0000x reference)
//
#include <hip/hip_runtime.h>
#include <hip/hip_bf16.h>
#include <math.h>

// STGCN fused, MFMA version, round 9: BARRIER-FREE wave-owned pipelines.
// Rounds 5-8 showed a latency-bound plateau at ~145us: 9 serialized
// {frag-load -> MFMA -> epilogue -> __syncthreads} stages, lockstepped waves,
// ~5-10us fixed cost per block that occupancy levers couldn't hide.
// Fix: each WAVE owns 4 (b,n) pairs end-to-end in its private 6KB LDS arena.
// No cross-wave dependencies -> ZERO __syncthreads. 16+ independent waves/CU
// hide each other's load latency / LDS waits / epilogues.
// Cost: M-padding (141 vs 114 MFMA/wave) and 8x redundant B-frag loads
// (L1/L2-hot, ~1.5KB/wave/stage set). sched_barrier(0) between stages keeps
// the compiler from hoisting next-stage loads (round-3 spill mode).

namespace {

constexpr int NT = 512;               // 8 waves; each owns 4 pairs
constexpr float INV_STD = 0.9999950000374997f; // 1/sqrt(1+1e-5)

typedef __attribute__((ext_vector_type(8))) short bf16x8;
typedef __attribute__((ext_vector_type(4))) float f32x4;

// d_ws layout (bf16 element offsets). All sections 16B-aligned (off%8==0).
constexpr int OFF_CHEB_A = 0;         // [32co][32k]
constexpr int OFF_CHEB_B = 1024;      // [32co][32k]
constexpr int OFF_A2     = 2048;      // P,Q,R x [64co][96k]
constexpr int OFF_B1     = 20480;     // P,Q,R x [32co][192k]
constexpr int OFF_B2     = 38912;     // P,Q,R x [16co][96k]
constexpr int OFF_S1B    = 43520;     // P,Q,R x [32co][32k] (zero-padded K)
constexpr int OFF_W1     = 46592;     // 113 x [64h][32k]
constexpr int OFF_W2     = 278016;    // 113 x [3o][64k]
// total ws bytes needed: (278016 + 21696) * 2 = 599,424

__device__ __forceinline__ unsigned short f2bf(float f){   // RNE f32->bf16 (prep)
  unsigned int u = __float_as_uint(f);
  u += 0x7fffu + ((u >> 16) & 1u);
  return (unsigned short)(u >> 16);
}
__device__ __forceinline__ unsigned short f2bf_fast(float f){  // native RNE
  return __bfloat16_as_ushort(__float2bfloat16(f));
}
__device__ __forceinline__ f32x4 bcast(float v){ f32x4 r; r[0]=v; r[1]=v; r[2]=v; r[3]=v; return r; }

struct Params {
  const float *x;
  const float *awp,*abp,*awq,*abq,*awr,*abr,*acw,*acb;
  const float *awp2,*abp2,*awq2,*abq2,*awr2,*abr2,*ag,*abeta;
  const float *bwp,*bbp,*bwq,*bbq,*bwr,*bbr,*bcw,*bcb;
  const float *bwp2,*bbp2,*bwq2,*bbq2,*bwr2,*bbr2,*bg,*bbeta;
  const float *w1,*b1,*w2,*b2;
  float *out;
};

// ---------------- prep: one-time weight transpose/convert into ws ----------------
__global__ void stgcn_prep(const Params p, unsigned short* __restrict__ W)
{
  int e = blockIdx.x*256 + threadIdx.x;
  if (e < 2048){                                    // cheb a/b [ci][co] -> [co][ci]
    const float* src = (e < 1024) ? p.acw : p.bcw;
    const int j = e & 1023, co = j >> 5, k = j & 31;
    W[e] = f2bf(src[k*32 + co]);
    return;
  }
  e -= 2048;
  if (e < 18432){                                   // a2: 3 x [64co][96k]
    const int mat = e / 6144, j = e % 6144, co = j / 96, k = j % 96;
    const float* src = mat==0 ? p.awp2 : (mat==1 ? p.awq2 : p.awr2);
    W[OFF_A2 + e] = f2bf(src[k*64 + co]);
    return;
  }
  e -= 18432;
  if (e < 18432){                                   // b1: 3 x [32co][192k]
    const int mat = e / 6144, j = e % 6144, co = j / 192, k = j % 192;
    const float* src = mat==0 ? p.bwp : (mat==1 ? p.bwq : p.bwr);
    W[OFF_B1 + e] = f2bf(src[k*32 + co]);
    return;
  }
  e -= 18432;
  if (e < 4608){                                    // b2: 3 x [16co][96k]
    const int mat = e / 1536, j = e % 1536, co = j / 96, k = j % 96;
    const float* src = mat==0 ? p.bwp2 : (mat==1 ? p.bwq2 : p.bwr2);
    W[OFF_B2 + e] = f2bf(src[k*16 + co]);
    return;
  }
  e -= 4608;
  if (e < 3072){                                    // s1: 3 x [32co][32k], k=tt*8+ci
    const int mat = e / 1024, j = e % 1024, co = j >> 5, k = j & 31;
    const int tt = k >> 3, ci = k & 7;
    const float* src = mat==0 ? p.awp : (mat==1 ? p.awq : p.awr);
    W[OFF_S1B + e] = (ci < 4 && tt < 3) ? f2bf(src[(tt*4+ci)*32 + co])
                                        : (unsigned short)0;
    return;
  }
  e -= 3072;
  if (e < 231424){ W[OFF_W1 + e] = f2bf(p.w1[e]); return; }  // [n][h][f] already B^T
  e -= 231424;
  if (e < 21696){ W[OFF_W2 + e] = f2bf(p.w2[e]); }           // [n][o][k] already B^T
}

// ---------------- per-wave MFMA stage ----------------
// Wave-private: aB/oB point into this wave's LDS arena (4 pairs).
// A row m=(pr,t), pr masked &3 so padded M rows re-read valid arena data
// (their outputs are discarded by the MROWS write guard).
// EPI: 0 = relu(acc+bias); 1 = relu(P*sig(Q)+R); 2 = EPI1 then relu(v*bn+bt).
template<int TOUT, int CIN, int NK, int RSTI, int PSTI, int RSTO, int PSTO,
         int KP, int EPI, int MTILES, int NTILES, int MROWS, int COUT>
__device__ __forceinline__ void wave_stage(
    const unsigned short* __restrict__ aB,
    const unsigned short* __restrict__ gW,
    unsigned short* __restrict__ oB,
    const float* __restrict__ gb0, const float* __restrict__ gb1,
    const float* __restrict__ gb2,
    const int lm, const int lk, const float bnsc, const float bnbt)
{
  constexpr int KB  = (NK > 3) ? 3 : NK;   // frag block (reg cap: 9 frags live)
  constexpr int NKB = NK / KB;
  #pragma unroll
  for (int Nt = 0; Nt < NTILES; ++Nt){
    const int col = Nt*16 + lm;
    const unsigned short* wbase = gW + col*KP + lk*8;
    const float b0 = gb0[col];
    float b1v = 0.f, b2v = 0.f;
    if constexpr (EPI >= 1){ b1v = gb1[col]; b2v = gb2[col]; }
    f32x4 aP[MTILES], aQ[MTILES], aR[MTILES];
    #pragma unroll
    for (int Mt = 0; Mt < MTILES; ++Mt){
      aP[Mt] = bcast(b0);
      if constexpr (EPI >= 1){ aQ[Mt] = bcast(b1v); aR[Mt] = bcast(b2v); }
    }
    #pragma unroll
    for (int kb = 0; kb < NKB; ++kb){
      bf16x8 wp[KB], wq[KB], wr[KB];
      #pragma unroll
      for (int s = 0; s < KB; ++s){
        const int ks = kb*KB + s;
        wp[s] = *reinterpret_cast<const bf16x8*>(wbase + ks*32);
        if constexpr (EPI >= 1){
          wq[s] = *reinterpret_cast<const bf16x8*>(wbase +   COUT*KP + ks*32);
          wr[s] = *reinterpret_cast<const bf16x8*>(wbase + 2*COUT*KP + ks*32);
        }
      }
      #pragma unroll
      for (int Mt = 0; Mt < MTILES; ++Mt){
        const int m   = Mt*16 + lm;
        const int prr = m / TOUT;
        const int pr  = prr & 3;                 // mask: padded rows read row pr-4
        const int t   = m - prr*TOUT;
        #pragma unroll
        for (int s = 0; s < KB; ++s){
          const int ks = kb*KB + s;
          int elem;
          if constexpr (CIN == 32) elem = pr*PSTI + (t + ks)*RSTI + lk*8;
          else                     elem = pr*PSTI + (t + (ks>>1))*RSTI + (ks&1)*32 + lk*8;
          const bf16x8 a = *reinterpret_cast<const bf16x8*>(aB + elem);
          aP[Mt] = __builtin_amdgcn_mfma_f32_16x16x32_bf16(a, wp[s], aP[Mt], 0,0,0);
          if constexpr (EPI >= 1){
            aQ[Mt] = __builtin_amdgcn_mfma_f32_16x16x32_bf16(a, wq[s], aQ[Mt], 0,0,0);
            aR[Mt] = __builtin_amdgcn_mfma_f32_16x16x32_bf16(a, wr[s], aR[Mt], 0,0,0);
          }
        }
      }
    }
    #pragma unroll
    for (int Mt = 0; Mt < MTILES; ++Mt){
      #pragma unroll
      for (int r = 0; r < 4; ++r){
        const int mo = Mt*16 + lk*4 + r;
        if constexpr (MROWS < MTILES*16){ if (mo >= MROWS) continue; }
        const int po = mo / TOUT;
        const int to = mo - po*TOUT;
        float v;
        if constexpr (EPI == 0) v = fmaxf(aP[Mt][r], 0.f);
        else {
          const float sig = 1.f/(1.f + __expf(-aQ[Mt][r]));
          v = fmaxf(fmaf(aP[Mt][r], sig, aR[Mt][r]), 0.f);
          if constexpr (EPI == 2) v = fmaxf(fmaf(v, bnsc, bnbt), 0.f);
        }
        oB[po*PSTO + to*RSTO + col] = f2bf_fast(v);
      }
    }
  }
}

// ---------------- main fused kernel: zero block barriers ----------------
// Per-wave arena 3008 bf16 elems (6016B): AH = [0,1728) ping, BH = [1728,3008) pong.
// 8 waves x 3008 = 24064 elems = 48,128 B LDS.
// Per-wave layouts (4 pairs, prl=0..3):
//   sxb (BH)  [prl*88 + t*8 + ci]   ci<4 real, rest 0; t=10 slot zero
//   h1  (AH)  [prl*320 + t*40 + c]  8t x 32c       h1c (BH) same
//   h2  (AH)  [prl*432 + t*72 + c]  6t x 64c
//   h3  (BH)  [prl*160 + t*40 + c]  4t x 32c       h3c (AH) same
//   h4  (BH)  [prl*40  + t*16 + c]  2t x 16c (flatten order)
//   hid (AH)  [prl*72  + h]         64h
__global__ __launch_bounds__(NT, 4) void stgcn_main(const Params p,
    const unsigned short* __restrict__ W)
{
  __shared__ __align__(16) unsigned short smem[24064];

  const int tid = threadIdx.x;
  const int l   = tid & 63;
  const int wid = tid >> 6;                  // 0..7
  const int lm  = l & 15;
  const int lk  = l >> 4;
  const int n   = blockIdx.x >> 5;           // b-fastest: 32 consecutive blocks share n
  const int b0  = (blockIdx.x & 31) * 32 + wid*4;   // this wave's first pair

  unsigned short* const AH = smem + wid*3008;
  unsigned short* const BH = AH + 1728;

  // ---- per-wave x staging: 4 pairs x 22 ushort4-chunks into BH ----
  #pragma unroll
  for (int ii = 0; ii < 2; ++ii){
    const int i = ii*64 + l;
    if (i < 88){
      const int prl = i / 22, c = i - prl*22;
      const int t   = c >> 1;
      unsigned short v0=0,v1=0,v2=0,v3=0;
      if (!(c & 1) && t < 10){
        const float4 xf = *reinterpret_cast<const float4*>(
            &p.x[(size_t)(((b0+prl)*10 + t)*113 + n)*4]);
        v0 = f2bf(xf.x); v1 = f2bf(xf.y); v2 = f2bf(xf.z); v3 = f2bf(xf.w);
      }
      ushort4 pk; pk.x=v0; pk.y=v1; pk.z=v2; pk.w=v3;
      *reinterpret_cast<ushort4*>(BH + prl*88 + c*4) = pk;
    }
  }
  __builtin_amdgcn_sched_barrier(0);

  // stage1: (10,4)->(8,32) gated conv, K padded 12->32. M=32(2) N=32(2)
  wave_stage<8,32,1, 8,88, 40,320, 32, 1, 2,2,32, 32>(
      BH, W+OFF_S1B, AH, p.abp, p.abq, p.abr, lm, lk, 0.f, 0.f);
  __builtin_amdgcn_sched_barrier(0);

  // cheb1: M=32(2) N=32(2) K=32
  wave_stage<8,32,1, 40,320, 40,320, 32, 0, 2,2,32, 32>(
      AH, W+OFF_CHEB_A, BH, p.acb, p.acb, p.acb, lm, lk, 0.f, 0.f);
  __builtin_amdgcn_sched_barrier(0);

  // stage3: (8,32)->(6,64) gated + BN(a). M=24(2 tiles, guarded) N=64(4) K=96
  {
    const float bnsc = INV_STD * p.ag[n], bnbt = p.abeta[n];
    wave_stage<6,32,3, 40,320, 72,432, 96, 2, 2,4,24, 64>(
        BH, W+OFF_A2, AH, p.abp2, p.abq2, p.abr2, lm, lk, bnsc, bnbt);
  }
  __builtin_amdgcn_sched_barrier(0);

  // stage4: (6,64)->(4,32) gated. M=16(1) N=32(2) K=192 (kb-split 2x9 frags)
  wave_stage<4,64,6, 72,432, 40,160, 192, 1, 1,2,16, 32>(
      AH, W+OFF_B1, BH, p.bbp, p.bbq, p.bbr, lm, lk, 0.f, 0.f);
  __builtin_amdgcn_sched_barrier(0);

  // cheb2: M=16(1) N=32(2) K=32
  wave_stage<4,32,1, 40,160, 40,160, 32, 0, 1,2,16, 32>(
      BH, W+OFF_CHEB_B, AH, p.bcb, p.bcb, p.bcb, lm, lk, 0.f, 0.f);
  __builtin_amdgcn_sched_barrier(0);

  // stage6: (4,32)->(2,16) gated + BN(b). M=8(1 tile, guarded) N=16(1) K=96
  {
    const float bnsc = INV_STD * p.bg[n], bnbt = p.bbeta[n];
    wave_stage<2,32,3, 40,160, 16,40, 96, 2, 1,1,8, 16>(
        AH, W+OFF_B2, BH, p.bbp2, p.bbq2, p.bbr2, lm, lk, bnsc, bnbt);
  }
  __builtin_amdgcn_sched_barrier(0);

  // mlp1: feat(32) -> hid(64). M=4(1 tile, guarded) N=64(4) K=32
  wave_stage<1,32,1, 16,40, 16,72, 32, 0, 1,4,4, 64>(
      BH, W+OFF_W1 + n*2048, AH, p.b1 + n*64, p.b1, p.b1, lm, lk, 0.f, 0.f);
  __builtin_amdgcn_sched_barrier(0);

  // mlp2: hid(64) -> 3. A row = lm&3 (pairs 0..3), cols 0..2 valid.
  {
    const unsigned short* WM2 = W + OFF_W2 + n*192;
    const int lmc = (lm < 3) ? lm : 0;         // clamp: stay inside W2 section
    const float bias = (lm < 3) ? p.b2[n*3 + lm] : 0.f;
    f32x4 acc = bcast(bias);
    #pragma unroll
    for (int ks = 0; ks < 2; ++ks){
      const bf16x8 a = *reinterpret_cast<const bf16x8*>(AH + (lm & 3)*72 + ks*32 + lk*8);
      const bf16x8 b = *reinterpret_cast<const bf16x8*>(WM2 + lmc*64 + ks*32 + lk*8);
      acc = __builtin_amdgcn_mfma_f32_16x16x32_bf16(a, b, acc, 0, 0, 0);
    }
    if (lm < 3){
      #pragma unroll
      for (int r = 0; r < 4; ++r){
        const int row = lk*4 + r;               // output pair index
        if (row < 4)
          p.out[(size_t)((b0+row)*113 + n)*3 + lm] = acc[r];
      }
    }
  }
}

} // namespace

extern "C" void kernel_launch(void* const* d_in, const int* in_sizes, int n_in,
                              void* d_out, int out_size, void* d_ws, size_t ws_size,
                              hipStream_t stream) {
  (void)in_sizes; (void)n_in; (void)ws_size; (void)out_size;
  Params p;
  p.x     = (const float*)d_in[0];
  // d_in[1] = edge_index (unused: ChebConv K=1 keeps only the identity term)
  p.awp   = (const float*)d_in[2];  p.abp   = (const float*)d_in[3];
  p.awq   = (const float*)d_in[4];  p.abq   = (const float*)d_in[5];
  p.awr   = (const float*)d_in[6];  p.abr   = (const float*)d_in[7];
  p.acw   = (const float*)d_in[8];  p.acb   = (const float*)d_in[9];
  p.awp2  = (const float*)d_in[10]; p.abp2  = (const float*)d_in[11];
  p.awq2  = (const float*)d_in[12]; p.abq2  = (const float*)d_in[13];
  p.awr2  = (const float*)d_in[14]; p.abr2  = (const float*)d_in[15];
  p.ag    = (const float*)d_in[16]; p.abeta = (const float*)d_in[17];
  p.bwp   = (const float*)d_in[18]; p.bbp   = (const float*)d_in[19];
  p.bwq   = (const float*)d_in[20]; p.bbq   = (const float*)d_in[21];
  p.bwr   = (const float*)d_in[22]; p.bbr   = (const float*)d_in[23];
  p.bcw   = (const float*)d_in[24]; p.bcb   = (const float*)d_in[25];
  p.bwp2  = (const float*)d_in[26]; p.bbp2  = (const float*)d_in[27];
  p.bwq2  = (const float*)d_in[28]; p.bbq2  = (const float*)d_in[29];
  p.bwr2  = (const float*)d_in[30]; p.bbr2  = (const float*)d_in[31];
  p.bg    = (const float*)d_in[32]; p.bbeta = (const float*)d_in[33];
  p.w1    = (const float*)d_in[34]; p.b1    = (const float*)d_in[35];
  p.w2    = (const float*)d_in[36]; p.b2    = (const float*)d_in[37];
  p.out   = (float*)d_out;

  unsigned short* W = (unsigned short*)d_ws;   // needs 599,424 bytes

  // prep: 299,712 work items
  stgcn_prep<<<1171, 256, 0, stream>>>(p, W);

  const int tiles = 113 * 32;  // 3616 blocks, b fastest within each n
  stgcn_main<<<tiles, NT, 0, stream>>>(p, W);
}

// Round 10
// 147.077 us; speedup vs baseline: 1.6311x; 1.6311x over previous
//
#include <hip/hip_runtime.h>
#include <hip/hip_bf16.h>
#include <math.h>

// STGCN fused, MFMA version, round 10.
// Round 9 post-mortem: wave-private pipelines quadrupled per-wave frag loads
// -> 240us. Round 8 (145us) remains base. Counter model: MFMA floor ~21us,
// VALU ~71us, wall 145us => half the time is stall. Occupancy pinned at 40%
// whenever VGPR~48-60 but 79% when VGPR=32 (round 6) => hypothesis: reported
// VGPR excludes AGPRs; true total ~110/wave => 4 waves/SIMD is the binder.
// Round 10 = round 8 + register diet to reach 6 waves/SIMD (3 resident blocks):
//   - __launch_bounds__(512,6)  (target <=85 total regs)
//   - stage3 reloads B-frags per M-job (9 live frags -> transient)
//   - #pragma unroll 1 on M-job loops (no cross-j live-range stretch)
// Schedule, layouts, barriers identical to round 8.

namespace {

constexpr int NT = 512;               // 8 waves
constexpr int NP = 32;                // (b,n) pairs per block (same n)
constexpr float INV_STD = 0.9999950000374997f; // 1/sqrt(1+1e-5)

typedef __attribute__((ext_vector_type(8))) short bf16x8;
typedef __attribute__((ext_vector_type(4))) float f32x4;

// d_ws layout (bf16 element offsets). All sections 16B-aligned (off%8==0).
constexpr int OFF_CHEB_A = 0;         // [32co][32k]
constexpr int OFF_CHEB_B = 1024;      // [32co][32k]
constexpr int OFF_A2     = 2048;      // P,Q,R x [64co][96k]
constexpr int OFF_B1     = 20480;     // P,Q,R x [32co][192k]
constexpr int OFF_B2     = 38912;     // P,Q,R x [16co][96k]
constexpr int OFF_S1B    = 43520;     // P,Q,R x [32co][32k] (zero-padded K)
constexpr int OFF_W1     = 46592;     // 113 x [64h][32k]
constexpr int OFF_W2     = 278016;    // 113 x [3o][64k]
// total ws bytes needed: (278016 + 21696) * 2 = 599,424

__device__ __forceinline__ unsigned short f2bf(float f){   // RNE f32->bf16 (prep)
  unsigned int u = __float_as_uint(f);
  u += 0x7fffu + ((u >> 16) & 1u);
  return (unsigned short)(u >> 16);
}
__device__ __forceinline__ unsigned short f2bf_fast(float f){  // native RNE
  return __bfloat16_as_ushort(__float2bfloat16(f));
}
__device__ __forceinline__ f32x4 bcast(float v){ f32x4 r; r[0]=v; r[1]=v; r[2]=v; r[3]=v; return r; }

struct Params {
  const float *x;
  const float *awp,*abp,*awq,*abq,*awr,*abr,*acw,*acb;
  const float *awp2,*abp2,*awq2,*abq2,*awr2,*abr2,*ag,*abeta;
  const float *bwp,*bbp,*bwq,*bbq,*bwr,*bbr,*bcw,*bcb;
  const float *bwp2,*bbp2,*bwq2,*bbq2,*bwr2,*bbr2,*bg,*bbeta;
  const float *w1,*b1,*w2,*b2;
  float *out;
};

// ---------------- prep: one-time weight transpose/convert into ws ----------------
__global__ void stgcn_prep(const Params p, unsigned short* __restrict__ W)
{
  int e = blockIdx.x*256 + threadIdx.x;
  if (e < 2048){                                    // cheb a/b [ci][co] -> [co][ci]
    const float* src = (e < 1024) ? p.acw : p.bcw;
    const int j = e & 1023, co = j >> 5, k = j & 31;
    W[e] = f2bf(src[k*32 + co]);
    return;
  }
  e -= 2048;
  if (e < 18432){                                   // a2: 3 x [64co][96k]
    const int mat = e / 6144, j = e % 6144, co = j / 96, k = j % 96;
    const float* src = mat==0 ? p.awp2 : (mat==1 ? p.awq2 : p.awr2);
    W[OFF_A2 + e] = f2bf(src[k*64 + co]);
    return;
  }
  e -= 18432;
  if (e < 18432){                                   // b1: 3 x [32co][192k]
    const int mat = e / 6144, j = e % 6144, co = j / 192, k = j % 192;
    const float* src = mat==0 ? p.bwp : (mat==1 ? p.bwq : p.bwr);
    W[OFF_B1 + e] = f2bf(src[k*32 + co]);
    return;
  }
  e -= 18432;
  if (e < 4608){                                    // b2: 3 x [16co][96k]
    const int mat = e / 1536, j = e % 1536, co = j / 96, k = j % 96;
    const float* src = mat==0 ? p.bwp2 : (mat==1 ? p.bwq2 : p.bwr2);
    W[OFF_B2 + e] = f2bf(src[k*16 + co]);
    return;
  }
  e -= 4608;
  if (e < 3072){                                    // s1: 3 x [32co][32k], k=tt*8+ci
    const int mat = e / 1024, j = e % 1024, co = j >> 5, k = j & 31;
    const int tt = k >> 3, ci = k & 7;
    const float* src = mat==0 ? p.awp : (mat==1 ? p.awq : p.awr);
    W[OFF_S1B + e] = (ci < 4 && tt < 3) ? f2bf(src[(tt*4+ci)*32 + co])
                                        : (unsigned short)0;
    return;
  }
  e -= 3072;
  if (e < 231424){ W[OFF_W1 + e] = f2bf(p.w1[e]); return; }  // [n][h][f] already B^T
  e -= 231424;
  if (e < 21696){ W[OFF_W2 + e] = f2bf(p.w2[e]); }           // [n][o][k] already B^T
}

// ---------------- generic MFMA stage ----------------
// A row m=(pr,t) in LDS; k-step ks reads 32 contiguous bf16.
// EPI: 0 = relu(acc+bias); 1 = relu(P*sig(Q)+R); 2 = EPI1 then relu(v*bn+bt).
// RELOADB: load B-frags inside the M-job loop (transient regs) instead of
// preloading (used for stage3, the register-fattest stage).
// M-job loop is unroll-1: no cross-j live-range stretch, small code.
template<int TOUT, int CIN, int COUT, int NK, int RSTI, int PSTI, int RSTO, int PSTO,
         int KP, int EPI, int MJOBS, int MSTEP, bool RELOADB>
__device__ __forceinline__ void mfma_stage(const unsigned short* __restrict__ aB,
    const unsigned short* __restrict__ gW, unsigned short* __restrict__ oB,
    const float* __restrict__ gb0, const float* __restrict__ gb1,
    const float* __restrict__ gb2,
    const int Mtile0, const int Ntile, const int lm, const int lk,
    const float bnsc, const float bnbt)
{
  const int col = Ntile*16 + lm;
  const unsigned short* wbase = gW + col*KP + lk*8;
  bf16x8 wp[NK], wq[NK], wr[NK];
  if constexpr (!RELOADB){
    #pragma unroll
    for (int ks = 0; ks < NK; ++ks){
      wp[ks] = *reinterpret_cast<const bf16x8*>(wbase + ks*32);
      if constexpr (EPI >= 1){
        wq[ks] = *reinterpret_cast<const bf16x8*>(wbase +   COUT*KP + ks*32);
        wr[ks] = *reinterpret_cast<const bf16x8*>(wbase + 2*COUT*KP + ks*32);
      }
    }
  }
  const float b0 = gb0[col];
  float b1v = 0.f, b2v = 0.f;
  if constexpr (EPI >= 1){ b1v = gb1[col]; b2v = gb2[col]; }

  #pragma unroll 1
  for (int j = 0; j < MJOBS; ++j){
    const int Mtile = Mtile0 + j*MSTEP;
    const int m  = Mtile*16 + lm;
    const int pr = m / TOUT;
    const int t  = m - pr*TOUT;
    f32x4 aP = bcast(b0), aQ, aR;
    if constexpr (EPI >= 1){ aQ = bcast(b1v); aR = bcast(b2v); }
    #pragma unroll
    for (int ks = 0; ks < NK; ++ks){
      bf16x8 fp, fq, fr;
      if constexpr (RELOADB){
        fp = *reinterpret_cast<const bf16x8*>(wbase + ks*32);
        if constexpr (EPI >= 1){
          fq = *reinterpret_cast<const bf16x8*>(wbase +   COUT*KP + ks*32);
          fr = *reinterpret_cast<const bf16x8*>(wbase + 2*COUT*KP + ks*32);
        }
      } else {
        fp = wp[ks];
        if constexpr (EPI >= 1){ fq = wq[ks]; fr = wr[ks]; }
      }
      int elem;
      if constexpr (CIN == 32) elem = pr*PSTI + (t + ks)*RSTI + lk*8;
      else                     elem = pr*PSTI + (t + (ks>>1))*RSTI + (ks&1)*32 + lk*8;
      const bf16x8 a = *reinterpret_cast<const bf16x8*>(aB + elem);
      aP = __builtin_amdgcn_mfma_f32_16x16x32_bf16(a, fp, aP, 0, 0, 0);
      if constexpr (EPI >= 1){
        aQ = __builtin_amdgcn_mfma_f32_16x16x32_bf16(a, fq, aQ, 0, 0, 0);
        aR = __builtin_amdgcn_mfma_f32_16x16x32_bf16(a, fr, aR, 0, 0, 0);
      }
    }
    #pragma unroll
    for (int r = 0; r < 4; ++r){
      const int mo = Mtile*16 + lk*4 + r;
      const int po = mo / TOUT;
      const int to = mo - po*TOUT;
      float v;
      if constexpr (EPI == 0) v = fmaxf(aP[r], 0.f);
      else {
        const float sig = 1.f/(1.f + __expf(-aQ[r]));
        v = fmaxf(fmaf(aP[r], sig, aR[r]), 0.f);
        if constexpr (EPI == 2) v = fmaxf(fmaf(v, bnsc, bnbt), 0.f);
      }
      oB[po*PSTO + to*RSTO + col] = f2bf_fast(v);
    }
  }
}

// ---------------- stage4 (K=192): k-outer / j-inner, 9 B-frags live ----------------
__device__ __forceinline__ void mfma_stage4(const unsigned short* __restrict__ aB,
    const unsigned short* __restrict__ gW, unsigned short* __restrict__ oB,
    const float* __restrict__ gb0, const float* __restrict__ gb1,
    const float* __restrict__ gb2,
    const int Mtile0, const int Ntile, const int lm, const int lk)
{
  const int col = Ntile*16 + lm;
  const unsigned short* wbase = gW + col*192 + lk*8;
  f32x4 aP[2], aQ[2], aR[2];
  {
    const float b0 = gb0[col], b1 = gb1[col], b2 = gb2[col];
    #pragma unroll
    for (int j=0;j<2;++j){ aP[j]=bcast(b0); aQ[j]=bcast(b1); aR[j]=bcast(b2); }
  }
  #pragma unroll 1
  for (int kb = 0; kb < 2; ++kb){
    bf16x8 wp[3], wq[3], wr[3];
    #pragma unroll
    for (int s = 0; s < 3; ++s){
      const int ks = kb*3 + s;
      wp[s] = *reinterpret_cast<const bf16x8*>(wbase +         ks*32);
      wq[s] = *reinterpret_cast<const bf16x8*>(wbase +  6144 + ks*32); // 32*192
      wr[s] = *reinterpret_cast<const bf16x8*>(wbase + 12288 + ks*32);
    }
    #pragma unroll
    for (int j = 0; j < 2; ++j){
      const int Mtile = Mtile0 + j*4;
      const int m  = Mtile*16 + lm;
      const int pr = m >> 2, t = m & 3;
      #pragma unroll
      for (int s = 0; s < 3; ++s){
        const int ks = kb*3 + s;
        const int elem = pr*432 + (t + (ks>>1))*72 + (ks&1)*32 + lk*8;
        const bf16x8 a = *reinterpret_cast<const bf16x8*>(aB + elem);
        aP[j] = __builtin_amdgcn_mfma_f32_16x16x32_bf16(a, wp[s], aP[j], 0,0,0);
        aQ[j] = __builtin_amdgcn_mfma_f32_16x16x32_bf16(a, wq[s], aQ[j], 0,0,0);
        aR[j] = __builtin_amdgcn_mfma_f32_16x16x32_bf16(a, wr[s], aR[j], 0,0,0);
      }
    }
  }
  #pragma unroll
  for (int j = 0; j < 2; ++j){
    const int Mtile = Mtile0 + j*4;
    #pragma unroll
    for (int r = 0; r < 4; ++r){
      const int mo = Mtile*16 + lk*4 + r;
      const int po = mo >> 2, to = mo & 3;
      const float sig = 1.f/(1.f + __expf(-aQ[j][r]));
      const float v = fmaxf(fmaf(aP[j][r], sig, aR[j][r]), 0.f);
      oB[po*160 + to*40 + col] = f2bf_fast(v);
    }
  }
}

// ---------------- main fused kernel ----------------
// LDS: one 48,128 B arena. bufA = smem[0..13823], bufB = smem[13824..24063],
// sxb ALIASES bufB (dead before cheb1 writes bufB).
// launch_bounds(512,6): compiler targets <=85 total regs (arch+acc) so 6
// waves/SIMD are schedulable -> 3 resident blocks. Stage3 frag-reload +
// unroll-1 M-job loops keep live registers under the cap without spill.
__global__ __launch_bounds__(NT, 6) void stgcn_main(const Params p,
    const unsigned short* __restrict__ W)
{
  __shared__ __align__(16) unsigned short smem[24064];   // 48,128 B
  unsigned short* const bufA = smem;            // 13824 elems (27648 B)
  unsigned short* const bufB = smem + 13824;    // 10240 elems (20480 B)
  unsigned short* const sxb  = bufB;            // 2816 elems, dead before cheb1

  const int tid = threadIdx.x;
  const int l   = tid & 63;
  const int wid = tid >> 6;     // 0..7
  const int lm  = l & 15;
  const int lk  = l >> 4;
  const int n   = blockIdx.x >> 5;          // b-fastest: 32 consecutive blocks
  const int b0  = (blockIdx.x & 31) * NP;   // share one n (weights L2-hot)

  // x tile: one 8B chunk per (pr, half-slot); even chunks get bf16(x), odd zeros
  for (int i = tid; i < NP*22; i += NT){
    const int pr = i / 22, c = i - pr*22;
    const int t  = c >> 1;
    unsigned short v0=0,v1=0,v2=0,v3=0;
    if (!(c & 1) && t < 10){
      const float4 xf = *reinterpret_cast<const float4*>(
          &p.x[(size_t)(((b0+pr)*10 + t)*113 + n)*4]);
      v0 = f2bf(xf.x); v1 = f2bf(xf.y); v2 = f2bf(xf.z); v3 = f2bf(xf.w);
    }
    ushort4 pk; pk.x=v0; pk.y=v1; pk.z=v2; pk.w=v3;
    *reinterpret_cast<ushort4*>(&sxb[i*4]) = pk;
  }
  __syncthreads();

  // stage1: (10,4)->(8,32) gated conv, K padded 12->32. M=256(16) N=32(2) -> bufA
  mfma_stage<8,32,32,1, 8,88, 40,320, 32, 1, 4,4, false>(
      sxb, W+OFF_S1B, bufA, p.abp, p.abq, p.abr, wid>>1, wid&1, lm, lk, 0.f, 0.f);
  __syncthreads();

  // cheb1: M=256(16) N=32(2) K=32 -> bufB (overwrites sxb region, now dead)
  mfma_stage<8,32,32,1, 40,320, 40,320, 32, 0, 4,4, false>(
      bufA, W+OFF_CHEB_A, bufB, p.acb, p.acb, p.acb, wid>>1, wid&1, lm, lk, 0.f, 0.f);
  __syncthreads();

  // stage3: (8,32)->(6,64) gated + BN(a). M=192(12) N=64(4) K=96 -> bufA
  // RELOADB: 9 frags loaded per M-job (transient) instead of held live.
  {
    const float bnsc = INV_STD * p.ag[n], bnbt = p.abeta[n];
    mfma_stage<6,32,64,3, 40,320, 72,432, 96, 2, 6,2, true>(
        bufB, W+OFF_A2, bufA, p.abp2, p.abq2, p.abr2, wid>>2, wid&3, lm, lk, bnsc, bnbt);
  }
  __syncthreads();

  // stage4: (6,64)->(4,32) gated. M=128(8) N=32(2) K=192 -> bufB
  mfma_stage4(bufA, W+OFF_B1, bufB, p.bbp, p.bbq, p.bbr, wid>>1, wid&1, lm, lk);
  __syncthreads();

  // cheb2: M=128(8) N=32(2) K=32 -> bufA
  mfma_stage<4,32,32,1, 40,160, 40,160, 32, 0, 2,4, false>(
      bufB, W+OFF_CHEB_B, bufA, p.bcb, p.bcb, p.bcb, wid>>1, wid&1, lm, lk, 0.f, 0.f);
  __syncthreads();

  // stage6: (4,32)->(2,16) gated + BN(b). M=64(4) N=16(1) K=96 -> bufB (h4)
  if (wid < 4){
    const float bnsc = INV_STD * p.bg[n], bnbt = p.bbeta[n];
    mfma_stage<2,32,16,3, 40,160, 16,40, 96, 2, 1,1, false>(
        bufA, W+OFF_B2, bufB, p.bbp2, p.bbq2, p.bbr2, wid, 0, lm, lk, bnsc, bnbt);
  }
  __syncthreads();

  // mlp1: feat(32) -> hid(64). M=32(2) N=64(4) K=32 -> bufA
  mfma_stage<1,32,64,1, 16,40, 16,72, 32, 0, 1,1, false>(
      bufB, W+OFF_W1 + n*2048, bufA, p.b1 + n*64, p.b1, p.b1, wid&1, wid>>1, lm, lk, 0.f, 0.f);
  __syncthreads();

  // mlp2: hid(64) -> 3. M=32(2), cols 0..2 valid (B cols 3..15 read garbage,
  // never written). Store f32 to global.
  if (wid < 2){
    const unsigned short* WM2 = W + OFF_W2 + n*192;
    const int Mtile = wid;
    const float bias = (lm < 3) ? p.b2[n*3 + lm] : 0.f;
    f32x4 acc = bcast(bias);
    #pragma unroll
    for (int ks = 0; ks < 2; ++ks){
      const bf16x8 a = *reinterpret_cast<const bf16x8*>(bufA + (Mtile*16+lm)*72 + ks*32 + lk*8);
      const bf16x8 b = *reinterpret_cast<const bf16x8*>(WM2 + lm*64 + ks*32 + lk*8);
      acc = __builtin_amdgcn_mfma_f32_16x16x32_bf16(a, b, acc, 0, 0, 0);
    }
    if (lm < 3){
      #pragma unroll
      for (int r = 0; r < 4; ++r){
        const int pr = Mtile*16 + lk*4 + r;
        p.out[(size_t)((b0+pr)*113 + n)*3 + lm] = acc[r];
      }
    }
  }
}

} // namespace

extern "C" void kernel_launch(void* const* d_in, const int* in_sizes, int n_in,
                              void* d_out, int out_size, void* d_ws, size_t ws_size,
                              hipStream_t stream) {
  (void)in_sizes; (void)n_in; (void)ws_size; (void)out_size;
  Params p;
  p.x     = (const float*)d_in[0];
  // d_in[1] = edge_index (unused: ChebConv K=1 keeps only the identity term)
  p.awp   = (const float*)d_in[2];  p.abp   = (const float*)d_in[3];
  p.awq   = (const float*)d_in[4];  p.abq   = (const float*)d_in[5];
  p.awr   = (const float*)d_in[6];  p.abr   = (const float*)d_in[7];
  p.acw   = (const float*)d_in[8];  p.acb   = (const float*)d_in[9];
  p.awp2  = (const float*)d_in[10]; p.abp2  = (const float*)d_in[11];
  p.awq2  = (const float*)d_in[12]; p.abq2  = (const float*)d_in[13];
  p.awr2  = (const float*)d_in[14]; p.abr2  = (const float*)d_in[15];
  p.ag    = (const float*)d_in[16]; p.abeta = (const float*)d_in[17];
  p.bwp   = (const float*)d_in[18]; p.bbp   = (const float*)d_in[19];
  p.bwq   = (const float*)d_in[20]; p.bbq   = (const float*)d_in[21];
  p.bwr   = (const float*)d_in[22]; p.bbr   = (const float*)d_in[23];
  p.bcw   = (const float*)d_in[24]; p.bcb   = (const float*)d_in[25];
  p.bwp2  = (const float*)d_in[26]; p.bbp2  = (const float*)d_in[27];
  p.bwq2  = (const float*)d_in[28]; p.bbq2  = (const float*)d_in[29];
  p.bwr2  = (const float*)d_in[30]; p.bbr2  = (const float*)d_in[31];
  p.bg    = (const float*)d_in[32]; p.bbeta = (const float*)d_in[33];
  p.w1    = (const float*)d_in[34]; p.b1    = (const float*)d_in[35];
  p.w2    = (const float*)d_in[36]; p.b2    = (const float*)d_in[37];
  p.out   = (float*)d_out;

  unsigned short* W = (unsigned short*)d_ws;   // needs 599,424 bytes

  // prep: 299,712 work items
  stgcn_prep<<<1171, 256, 0, stream>>>(p, W);

  const int tiles = 113 * 32;  // 3616, b fastest within each n
  stgcn_main<<<tiles, NT, 0, stream>>>(p, W);
}

// Round 11
// 138.714 us; speedup vs baseline: 1.7294x; 1.0603x over previous
//
#include <hip/hip_runtime.h>
#include <hip/hip_bf16.h>
#include <math.h>

// STGCN fused, MFMA version, round 11: OPERAND-SWAPPED epilogue.
// Round 10 falsified the occupancy theory (40->56% occ, dur flat 147us):
// a per-CU throughput resource is saturated. Tally: ~912 ds_read_b128 +
// ~1376 scalar ds_write_u16 per block (~60% of wall on the LDS pipe) +
// VALU coupled at 48%. The u16 scatter exists because C gives each lane a
// COLUMN (4 rows x 1 col). Fix: 16x16x32 A/B lane maps are symmetric, so
// swap roles: weights->A slot, activations->B slot. Read addresses are
// UNCHANGED; C comes out transposed: each lane holds 4 consecutive co for
// one m=(pr,t) -> one ds_write_b64 per 4 outputs, one pr/t div per 4,
// float4 bias loads. Same MFMA count, identical bf16 numerics.

namespace {

constexpr int NT = 512;               // 8 waves
constexpr int NP = 32;                // (b,n) pairs per block (same n)
constexpr float INV_STD = 0.9999950000374997f; // 1/sqrt(1+1e-5)

typedef __attribute__((ext_vector_type(8))) short bf16x8;
typedef __attribute__((ext_vector_type(4))) float f32x4;

// d_ws layout (bf16 element offsets). All sections 16B-aligned (off%8==0).
constexpr int OFF_CHEB_A = 0;         // [32co][32k]
constexpr int OFF_CHEB_B = 1024;      // [32co][32k]
constexpr int OFF_A2     = 2048;      // P,Q,R x [64co][96k]
constexpr int OFF_B1     = 20480;     // P,Q,R x [32co][192k]
constexpr int OFF_B2     = 38912;     // P,Q,R x [16co][96k]
constexpr int OFF_S1B    = 43520;     // P,Q,R x [32co][32k] (zero-padded K)
constexpr int OFF_W1     = 46592;     // 113 x [64h][32k]
constexpr int OFF_W2     = 278016;    // 113 x [3o][64k]
// total ws bytes needed: (278016 + 21696) * 2 = 599,424

__device__ __forceinline__ unsigned short f2bf(float f){   // RNE f32->bf16 (prep)
  unsigned int u = __float_as_uint(f);
  u += 0x7fffu + ((u >> 16) & 1u);
  return (unsigned short)(u >> 16);
}
__device__ __forceinline__ unsigned short f2bf_fast(float f){  // native RNE
  return __bfloat16_as_ushort(__float2bfloat16(f));
}
__device__ __forceinline__ f32x4 bcast(float v){ f32x4 r; r[0]=v; r[1]=v; r[2]=v; r[3]=v; return r; }

struct Params {
  const float *x;
  const float *awp,*abp,*awq,*abq,*awr,*abr,*acw,*acb;
  const float *awp2,*abp2,*awq2,*abq2,*awr2,*abr2,*ag,*abeta;
  const float *bwp,*bbp,*bwq,*bbq,*bwr,*bbr,*bcw,*bcb;
  const float *bwp2,*bbp2,*bwq2,*bbq2,*bwr2,*bbr2,*bg,*bbeta;
  const float *w1,*b1,*w2,*b2;
  float *out;
};

// ---------------- prep: one-time weight transpose/convert into ws ----------------
__global__ void stgcn_prep(const Params p, unsigned short* __restrict__ W)
{
  int e = blockIdx.x*256 + threadIdx.x;
  if (e < 2048){                                    // cheb a/b [ci][co] -> [co][ci]
    const float* src = (e < 1024) ? p.acw : p.bcw;
    const int j = e & 1023, co = j >> 5, k = j & 31;
    W[e] = f2bf(src[k*32 + co]);
    return;
  }
  e -= 2048;
  if (e < 18432){                                   // a2: 3 x [64co][96k]
    const int mat = e / 6144, j = e % 6144, co = j / 96, k = j % 96;
    const float* src = mat==0 ? p.awp2 : (mat==1 ? p.awq2 : p.awr2);
    W[OFF_A2 + e] = f2bf(src[k*64 + co]);
    return;
  }
  e -= 18432;
  if (e < 18432){                                   // b1: 3 x [32co][192k]
    const int mat = e / 6144, j = e % 6144, co = j / 192, k = j % 192;
    const float* src = mat==0 ? p.bwp : (mat==1 ? p.bwq : p.bwr);
    W[OFF_B1 + e] = f2bf(src[k*32 + co]);
    return;
  }
  e -= 18432;
  if (e < 4608){                                    // b2: 3 x [16co][96k]
    const int mat = e / 1536, j = e % 1536, co = j / 96, k = j % 96;
    const float* src = mat==0 ? p.bwp2 : (mat==1 ? p.bwq2 : p.bwr2);
    W[OFF_B2 + e] = f2bf(src[k*16 + co]);
    return;
  }
  e -= 4608;
  if (e < 3072){                                    // s1: 3 x [32co][32k], k=tt*8+ci
    const int mat = e / 1024, j = e % 1024, co = j >> 5, k = j & 31;
    const int tt = k >> 3, ci = k & 7;
    const float* src = mat==0 ? p.awp : (mat==1 ? p.awq : p.awr);
    W[OFF_S1B + e] = (ci < 4 && tt < 3) ? f2bf(src[(tt*4+ci)*32 + co])
                                        : (unsigned short)0;
    return;
  }
  e -= 3072;
  if (e < 231424){ W[OFF_W1 + e] = f2bf(p.w1[e]); return; }  // [n][h][f] already B^T
  e -= 231424;
  if (e < 21696){ W[OFF_W2 + e] = f2bf(p.w2[e]); }           // [n][o][k] already B^T
}

// ---------------- generic MFMA stage (operand-swapped) ----------------
// Weights are the A operand (row = co = Ntile*16+lm), activations are B
// (col = m = Mtile*16+lm). Read addresses identical to the unswapped form.
// C: lane holds co = Ntile*16 + lk*4 + r (4 consecutive) for ONE m ->
// epilogue is a single ushort4 store + float4 bias init.
// EPI: 0 = relu(acc+bias); 1 = relu(P*sig(Q)+R); 2 = EPI1 then relu(v*bn+bt).
template<int TOUT, int CIN, int COUT, int NK, int RSTI, int PSTI, int RSTO, int PSTO,
         int KP, int EPI, int MJOBS, int MSTEP, bool RELOADB>
__device__ __forceinline__ void mfma_stage(const unsigned short* __restrict__ aB,
    const unsigned short* __restrict__ gW, unsigned short* __restrict__ oB,
    const float* __restrict__ gb0, const float* __restrict__ gb1,
    const float* __restrict__ gb2,
    const int Mtile0, const int Ntile, const int lm, const int lk,
    const float bnsc, const float bnbt)
{
  const unsigned short* wbase = gW + (Ntile*16 + lm)*KP + lk*8;
  const int colbase = Ntile*16 + lk*4;      // this lane's 4 output channels
  bf16x8 wp[NK], wq[NK], wr[NK];
  if constexpr (!RELOADB){
    #pragma unroll
    for (int ks = 0; ks < NK; ++ks){
      wp[ks] = *reinterpret_cast<const bf16x8*>(wbase + ks*32);
      if constexpr (EPI >= 1){
        wq[ks] = *reinterpret_cast<const bf16x8*>(wbase +   COUT*KP + ks*32);
        wr[ks] = *reinterpret_cast<const bf16x8*>(wbase + 2*COUT*KP + ks*32);
      }
    }
  }
  const f32x4 b0v = *reinterpret_cast<const f32x4*>(gb0 + colbase);
  f32x4 b1v, b2v;
  if constexpr (EPI >= 1){
    b1v = *reinterpret_cast<const f32x4*>(gb1 + colbase);
    b2v = *reinterpret_cast<const f32x4*>(gb2 + colbase);
  }

  #pragma unroll 1
  for (int j = 0; j < MJOBS; ++j){
    const int m  = (Mtile0 + j*MSTEP)*16 + lm;
    const int pr = m / TOUT;
    const int t  = m - pr*TOUT;
    f32x4 aP = b0v, aQ, aR;
    if constexpr (EPI >= 1){ aQ = b1v; aR = b2v; }
    #pragma unroll
    for (int ks = 0; ks < NK; ++ks){
      bf16x8 fp, fq, fr;
      if constexpr (RELOADB){
        fp = *reinterpret_cast<const bf16x8*>(wbase + ks*32);
        if constexpr (EPI >= 1){
          fq = *reinterpret_cast<const bf16x8*>(wbase +   COUT*KP + ks*32);
          fr = *reinterpret_cast<const bf16x8*>(wbase + 2*COUT*KP + ks*32);
        }
      } else {
        fp = wp[ks];
        if constexpr (EPI >= 1){ fq = wq[ks]; fr = wr[ks]; }
      }
      int elem;
      if constexpr (CIN == 32) elem = pr*PSTI + (t + ks)*RSTI + lk*8;
      else                     elem = pr*PSTI + (t + (ks>>1))*RSTI + (ks&1)*32 + lk*8;
      const bf16x8 a = *reinterpret_cast<const bf16x8*>(aB + elem);
      aP = __builtin_amdgcn_mfma_f32_16x16x32_bf16(fp, a, aP, 0, 0, 0);
      if constexpr (EPI >= 1){
        aQ = __builtin_amdgcn_mfma_f32_16x16x32_bf16(fq, a, aQ, 0, 0, 0);
        aR = __builtin_amdgcn_mfma_f32_16x16x32_bf16(fr, a, aR, 0, 0, 0);
      }
    }
    ushort4 pk;
    unsigned short pv[4];
    #pragma unroll
    for (int r = 0; r < 4; ++r){
      float v;
      if constexpr (EPI == 0) v = fmaxf(aP[r], 0.f);
      else {
        const float sig = 1.f/(1.f + __expf(-aQ[r]));
        v = fmaxf(fmaf(aP[r], sig, aR[r]), 0.f);
        if constexpr (EPI == 2) v = fmaxf(fmaf(v, bnsc, bnbt), 0.f);
      }
      pv[r] = f2bf_fast(v);
    }
    pk.x = pv[0]; pk.y = pv[1]; pk.z = pv[2]; pk.w = pv[3];
    *reinterpret_cast<ushort4*>(oB + pr*PSTO + t*RSTO + colbase) = pk;
  }
}

// ---------------- stage4 (K=192): k-outer / j-inner, swapped ----------------
__device__ __forceinline__ void mfma_stage4(const unsigned short* __restrict__ aB,
    const unsigned short* __restrict__ gW, unsigned short* __restrict__ oB,
    const float* __restrict__ gb0, const float* __restrict__ gb1,
    const float* __restrict__ gb2,
    const int Mtile0, const int Ntile, const int lm, const int lk)
{
  const unsigned short* wbase = gW + (Ntile*16 + lm)*192 + lk*8;
  const int colbase = Ntile*16 + lk*4;
  f32x4 aP[2], aQ[2], aR[2];
  {
    const f32x4 b0v = *reinterpret_cast<const f32x4*>(gb0 + colbase);
    const f32x4 b1v = *reinterpret_cast<const f32x4*>(gb1 + colbase);
    const f32x4 b2v = *reinterpret_cast<const f32x4*>(gb2 + colbase);
    #pragma unroll
    for (int j=0;j<2;++j){ aP[j]=b0v; aQ[j]=b1v; aR[j]=b2v; }
  }
  #pragma unroll 1
  for (int kb = 0; kb < 2; ++kb){
    bf16x8 wp[3], wq[3], wr[3];
    #pragma unroll
    for (int s = 0; s < 3; ++s){
      const int ks = kb*3 + s;
      wp[s] = *reinterpret_cast<const bf16x8*>(wbase +         ks*32);
      wq[s] = *reinterpret_cast<const bf16x8*>(wbase +  6144 + ks*32); // 32*192
      wr[s] = *reinterpret_cast<const bf16x8*>(wbase + 12288 + ks*32);
    }
    #pragma unroll
    for (int j = 0; j < 2; ++j){
      const int m  = (Mtile0 + j*4)*16 + lm;
      const int pr = m >> 2, t = m & 3;
      #pragma unroll
      for (int s = 0; s < 3; ++s){
        const int ks = kb*3 + s;
        const int elem = pr*432 + (t + (ks>>1))*72 + (ks&1)*32 + lk*8;
        const bf16x8 a = *reinterpret_cast<const bf16x8*>(aB + elem);
        aP[j] = __builtin_amdgcn_mfma_f32_16x16x32_bf16(wp[s], a, aP[j], 0,0,0);
        aQ[j] = __builtin_amdgcn_mfma_f32_16x16x32_bf16(wq[s], a, aQ[j], 0,0,0);
        aR[j] = __builtin_amdgcn_mfma_f32_16x16x32_bf16(wr[s], a, aR[j], 0,0,0);
      }
    }
  }
  #pragma unroll
  for (int j = 0; j < 2; ++j){
    const int m  = (Mtile0 + j*4)*16 + lm;
    const int pr = m >> 2, t = m & 3;
    ushort4 pk;
    unsigned short pv[4];
    #pragma unroll
    for (int r = 0; r < 4; ++r){
      const float sig = 1.f/(1.f + __expf(-aQ[j][r]));
      pv[r] = f2bf_fast(fmaxf(fmaf(aP[j][r], sig, aR[j][r]), 0.f));
    }
    pk.x = pv[0]; pk.y = pv[1]; pk.z = pv[2]; pk.w = pv[3];
    *reinterpret_cast<ushort4*>(oB + pr*160 + t*40 + colbase) = pk;
  }
}

// ---------------- main fused kernel ----------------
// LDS: one 48,128 B arena. bufA = smem[0..13823], bufB = smem[13824..24063],
// sxb ALIASES bufB (dead before cheb1 writes bufB).
// launch_bounds(512,6) + stage3 frag-reload + unroll-1 M loops (r10 codegen).
__global__ __launch_bounds__(NT, 6) void stgcn_main(const Params p,
    const unsigned short* __restrict__ W)
{
  __shared__ __align__(16) unsigned short smem[24064];   // 48,128 B
  unsigned short* const bufA = smem;            // 13824 elems (27648 B)
  unsigned short* const bufB = smem + 13824;    // 10240 elems (20480 B)
  unsigned short* const sxb  = bufB;            // 2816 elems, dead before cheb1

  const int tid = threadIdx.x;
  const int l   = tid & 63;
  const int wid = tid >> 6;     // 0..7
  const int lm  = l & 15;
  const int lk  = l >> 4;
  const int n   = blockIdx.x >> 5;          // b-fastest: 32 consecutive blocks
  const int b0  = (blockIdx.x & 31) * NP;   // share one n (weights L2-hot)

  // x tile: one 8B chunk per (pr, half-slot); even chunks get bf16(x), odd zeros
  for (int i = tid; i < NP*22; i += NT){
    const int pr = i / 22, c = i - pr*22;
    const int t  = c >> 1;
    unsigned short v0=0,v1=0,v2=0,v3=0;
    if (!(c & 1) && t < 10){
      const float4 xf = *reinterpret_cast<const float4*>(
          &p.x[(size_t)(((b0+pr)*10 + t)*113 + n)*4]);
      v0 = f2bf(xf.x); v1 = f2bf(xf.y); v2 = f2bf(xf.z); v3 = f2bf(xf.w);
    }
    ushort4 pk; pk.x=v0; pk.y=v1; pk.z=v2; pk.w=v3;
    *reinterpret_cast<ushort4*>(&sxb[i*4]) = pk;
  }
  __syncthreads();

  // stage1: (10,4)->(8,32) gated conv, K padded 12->32. M=256(16) N=32(2) -> bufA
  mfma_stage<8,32,32,1, 8,88, 40,320, 32, 1, 4,4, false>(
      sxb, W+OFF_S1B, bufA, p.abp, p.abq, p.abr, wid>>1, wid&1, lm, lk, 0.f, 0.f);
  __syncthreads();

  // cheb1: M=256(16) N=32(2) K=32 -> bufB (overwrites sxb region, now dead)
  mfma_stage<8,32,32,1, 40,320, 40,320, 32, 0, 4,4, false>(
      bufA, W+OFF_CHEB_A, bufB, p.acb, p.acb, p.acb, wid>>1, wid&1, lm, lk, 0.f, 0.f);
  __syncthreads();

  // stage3: (8,32)->(6,64) gated + BN(a). M=192(12) N=64(4) K=96 -> bufA
  {
    const float bnsc = INV_STD * p.ag[n], bnbt = p.abeta[n];
    mfma_stage<6,32,64,3, 40,320, 72,432, 96, 2, 6,2, true>(
        bufB, W+OFF_A2, bufA, p.abp2, p.abq2, p.abr2, wid>>2, wid&3, lm, lk, bnsc, bnbt);
  }
  __syncthreads();

  // stage4: (6,64)->(4,32) gated. M=128(8) N=32(2) K=192 -> bufB
  mfma_stage4(bufA, W+OFF_B1, bufB, p.bbp, p.bbq, p.bbr, wid>>1, wid&1, lm, lk);
  __syncthreads();

  // cheb2: M=128(8) N=32(2) K=32 -> bufA
  mfma_stage<4,32,32,1, 40,160, 40,160, 32, 0, 2,4, false>(
      bufB, W+OFF_CHEB_B, bufA, p.bcb, p.bcb, p.bcb, wid>>1, wid&1, lm, lk, 0.f, 0.f);
  __syncthreads();

  // stage6: (4,32)->(2,16) gated + BN(b). M=64(4) N=16(1) K=96 -> bufB (h4)
  if (wid < 4){
    const float bnsc = INV_STD * p.bg[n], bnbt = p.bbeta[n];
    mfma_stage<2,32,16,3, 40,160, 16,40, 96, 2, 1,1, false>(
        bufA, W+OFF_B2, bufB, p.bbp2, p.bbq2, p.bbr2, wid, 0, lm, lk, bnsc, bnbt);
  }
  __syncthreads();

  // mlp1: feat(32) -> hid(64). M=32(2) N=64(4) K=32 -> bufA
  mfma_stage<1,32,64,1, 16,40, 16,72, 32, 0, 1,1, false>(
      bufB, W+OFF_W1 + n*2048, bufA, p.b1 + n*64, p.b1, p.b1, wid&1, wid>>1, lm, lk, 0.f, 0.f);
  __syncthreads();

  // mlp2: hid(64) -> 3, swapped. C: row=o=lk*4+r, col=m=Mtile*16+lm.
  // Only lk==0, r<3 valid; each such lane stores 3 consecutive f32.
  if (wid < 2){
    const unsigned short* WM2 = W + OFF_W2 + n*192;
    const int Mtile = wid;
    const int m = Mtile*16 + lm;
    const int lmo = (lm < 3) ? lm : 0;       // clamp A-row into valid W2 rows
    f32x4 acc = bcast(0.f);
    if (lk == 0){ acc[0]=p.b2[n*3]; acc[1]=p.b2[n*3+1]; acc[2]=p.b2[n*3+2]; }
    #pragma unroll
    for (int ks = 0; ks < 2; ++ks){
      const bf16x8 aw = *reinterpret_cast<const bf16x8*>(WM2 + lmo*64 + ks*32 + lk*8);
      const bf16x8 bh = *reinterpret_cast<const bf16x8*>(bufA + m*72 + ks*32 + lk*8);
      acc = __builtin_amdgcn_mfma_f32_16x16x32_bf16(aw, bh, acc, 0, 0, 0);
    }
    if (lk == 0){
      float* op = p.out + (size_t)((b0 + m)*113 + n)*3;
      op[0] = acc[0]; op[1] = acc[1]; op[2] = acc[2];
    }
  }
}

} // namespace

extern "C" void kernel_launch(void* const* d_in, const int* in_sizes, int n_in,
                              void* d_out, int out_size, void* d_ws, size_t ws_size,
                              hipStream_t stream) {
  (void)in_sizes; (void)n_in; (void)ws_size; (void)out_size;
  Params p;
  p.x     = (const float*)d_in[0];
  // d_in[1] = edge_index (unused: ChebConv K=1 keeps only the identity term)
  p.awp   = (const float*)d_in[2];  p.abp   = (const float*)d_in[3];
  p.awq   = (const float*)d_in[4];  p.abq   = (const float*)d_in[5];
  p.awr   = (const float*)d_in[6];  p.abr   = (const float*)d_in[7];
  p.acw   = (const float*)d_in[8];  p.acb   = (const float*)d_in[9];
  p.awp2  = (const float*)d_in[10]; p.abp2  = (const float*)d_in[11];
  p.awq2  = (const float*)d_in[12]; p.abq2  = (const float*)d_in[13];
  p.awr2  = (const float*)d_in[14]; p.abr2  = (const float*)d_in[15];
  p.ag    = (const float*)d_in[16]; p.abeta = (const float*)d_in[17];
  p.bwp   = (const float*)d_in[18]; p.bbp   = (const float*)d_in[19];
  p.bwq   = (const float*)d_in[20]; p.bbq   = (const float*)d_in[21];
  p.bwr   = (const float*)d_in[22]; p.bbr   = (const float*)d_in[23];
  p.bcw   = (const float*)d_in[24]; p.bcb   = (const float*)d_in[25];
  p.bwp2  = (const float*)d_in[26]; p.bbp2  = (const float*)d_in[27];
  p.bwq2  = (const float*)d_in[28]; p.bbq2  = (const float*)d_in[29];
  p.bwr2  = (const float*)d_in[30]; p.bbr2  = (const float*)d_in[31];
  p.bg    = (const float*)d_in[32]; p.bbeta = (const float*)d_in[33];
  p.w1    = (const float*)d_in[34]; p.b1    = (const float*)d_in[35];
  p.w2    = (const float*)d_in[36]; p.b2    = (const float*)d_in[37];
  p.out   = (float*)d_out;

  unsigned short* W = (unsigned short*)d_ws;   // needs 599,424 bytes

  // prep: 299,712 work items
  stgcn_prep<<<1171, 256, 0, stream>>>(p, W);

  const int tiles = 113 * 32;  // 3616, b fastest within each n
  stgcn_main<<<tiles, NT, 0, stream>>>(p, W);
}